// Round 4
// baseline (507.543 us; speedup 1.0000x reference)
//
#include <hip/hip_runtime.h>
#include <hip/hip_bf16.h>

#define N_NODES 8192
#define D_IN    512
#define H       256
#define D_OUT   16
#define K_CL    16
#define MAXN    96

// flat output element offsets (dtype-agnostic): output | Z_1 | Z_0 | score
#define OUT_OFF 0
#define Z1_OFF  131072
#define Z0_OFF  262144
#define SC_OFF  2359296

typedef unsigned int   u32;
typedef unsigned short u16;
typedef __attribute__((ext_vector_type(8))) short bf16x8;
typedef __attribute__((ext_vector_type(4))) float f32x4;

__device__ __forceinline__ float load_in(const void* p, int bf, size_t idx) {
    if (bf) { u32 w = ((const u16*)p)[idx]; return __uint_as_float(w << 16); }
    return ((const float*)p)[idx];
}
__device__ __forceinline__ void store_out(void* p, int bf, size_t idx, float v) {
    if (bf) ((__hip_bfloat16*)p)[idx] = __float2bfloat16(v);
    else    ((float*)p)[idx] = v;
}
// adj = max(adj, I) guarantees adj[0][0] == 1.0.
// fp32: word0 == 0x3F800000 exactly. bf16: word0 == 0x00003F80 or 0x3F803F80.
__device__ __forceinline__ int detect_bf(const void* adj) {
    return ((const u32*)adj)[0] != 0x3F800000u;
}
__device__ __forceinline__ float bf2f(u32 h) { return __uint_as_float(h << 16); }

// merged prep: blocks 0..31 transpose W -> Wt (bf16 [H][D_IN]); blocks 32..65 copy small params
__global__ __launch_bounds__(256) void k_prep(
    const void* __restrict__ wraw, const void* av, const void* C_a, const void* Wgcn,
    const void* __restrict__ adj,
    u16* __restrict__ Wt, float* a_f, float* Ca_f, float* Wg_f)
{
    int bf = detect_bf(adj);
    int b = blockIdx.x, tid = threadIdx.x;
    if (b >= 32) {
        int i = (b - 32) * 256 + tid;
        if (i < 512)        a_f[i]         = load_in(av,   bf, i);
        else if (i < 4608)  Ca_f[i - 512]  = load_in(C_a,  bf, i - 512);
        else if (i < 8704)  Wg_f[i - 4608] = load_in(Wgcn, bf, i - 4608);
        return;
    }
    __shared__ float tile[64][65];
    int k0 = (b >> 2) * 64, h0 = (b & 3) * 64;
    int hh = tid & 63, kk = tid >> 6;
    #pragma unroll
    for (int p = 0; p < 16; p++) {
        int k = kk * 16 + p;
        tile[k][hh] = load_in(wraw, bf, (size_t)(k0 + k) * H + h0 + hh);
    }
    __syncthreads();
    int kc = tid & 63, hr = tid >> 6;
    #pragma unroll
    for (int p = 0; p < 16; p++) {
        int h = hr * 16 + p;
        __hip_bfloat16 bb = __float2bfloat16(tile[kc][h]);
        Wt[(size_t)(h0 + h) * D_IN + k0 + kc] = *(u16*)&bb;
    }
}

// ---- dedicated streaming adjacency scan -> per-row neighbor lists ----
// grid-stride, 4-deep load clauses, ONE rare branch per 64B group.
// ~140K hits total -> global atomics negligible. ncnt must be pre-zeroed.
__global__ __launch_bounds__(256) void k_scan(
    const void* __restrict__ adjraw,
    int* __restrict__ ncnt, u16* __restrict__ nidx)
{
    const int bf = detect_bf(adjraw);
    const int gid = blockIdx.x * 256 + threadIdx.x;     // 524288 threads
    const int NT = 2048 * 256;
    const uint4* A = (const uint4*)adjraw;
    if (bf) {
        // 8192*8192 u16 = 128MB = 8M uint4 chunks; 16 chunks/thread
        #pragma unroll
        for (int g = 0; g < 4; g++) {
            uint4 r[4];
            #pragma unroll
            for (int u = 0; u < 4; u++)
                r[u] = A[(size_t)(g * 4 + u) * NT + gid];
            u32 any = 0;
            #pragma unroll
            for (int u = 0; u < 4; u++) any |= r[u].x | r[u].y | r[u].z | r[u].w;
            if (any) {
                #pragma unroll
                for (int u = 0; u < 4; u++) {
                    size_t w0 = ((size_t)(g * 4 + u) * NT + gid) * 8;  // u16 index
                    u32 ws[4] = {r[u].x, r[u].y, r[u].z, r[u].w};
                    #pragma unroll
                    for (int q = 0; q < 4; q++) {
                        if (ws[q] & 0xFFFFu) {
                            size_t i = w0 + q * 2;
                            int row = (int)(i >> 13), col = (int)(i & 8191);
                            int p = atomicAdd(&ncnt[row], 1);
                            if (p < MAXN) nidx[(size_t)row * MAXN + p] = (u16)col;
                        }
                        if (ws[q] >> 16) {
                            size_t i = w0 + q * 2 + 1;
                            int row = (int)(i >> 13), col = (int)(i & 8191);
                            int p = atomicAdd(&ncnt[row], 1);
                            if (p < MAXN) nidx[(size_t)row * MAXN + p] = (u16)col;
                        }
                    }
                }
            }
        }
    } else {
        // 8192*8192 f32 = 256MB = 16M uint4 chunks; 32 chunks/thread
        #pragma unroll
        for (int g = 0; g < 8; g++) {
            uint4 r[4];
            #pragma unroll
            for (int u = 0; u < 4; u++)
                r[u] = A[(size_t)(g * 4 + u) * NT + gid];
            u32 any = 0;
            #pragma unroll
            for (int u = 0; u < 4; u++) any |= r[u].x | r[u].y | r[u].z | r[u].w;
            if (any) {
                #pragma unroll
                for (int u = 0; u < 4; u++) {
                    size_t f0 = ((size_t)(g * 4 + u) * NT + gid) * 4;  // f32 index
                    u32 ws[4] = {r[u].x, r[u].y, r[u].z, r[u].w};
                    #pragma unroll
                    for (int q = 0; q < 4; q++) {
                        if (ws[q]) {                     // entries are 0.0f or 1.0f
                            size_t i = f0 + q;
                            int row = (int)(i >> 13), col = (int)(i & 8191);
                            int p = atomicAdd(&ncnt[row], 1);
                            if (p < MAXN) nidx[(size_t)row * MAXN + p] = (u16)col;
                        }
                    }
                }
            }
        }
    }
}

__global__ __launch_bounds__(256) void k_gemm_wh(
    const void* __restrict__ xraw, const void* __restrict__ wraw,
    const u16* __restrict__ Wt, const void* __restrict__ adj,
    float* __restrict__ Wh, u16* __restrict__ Whb)
{
    int bf = detect_bf(adj);
    __shared__ float xs[32][68];
    __shared__ float ws_[32][68];
    int tid = threadIdx.x;
    int bm = blockIdx.x >> 2, bn = blockIdx.x & 3;
    int m0 = bm * 64, n0 = bn * 64;

    if (bf) {
        // ---- bf16 MFMA path: 64x64 tile, 4 waves, each wave 32x32 ----
        int wave = tid >> 6, lane = tid & 63;
        int wr = wave >> 1, wc = wave & 1;
        int r0 = m0 + wr * 32, c0 = n0 + wc * 32;
        int lr = lane & 15, lk = lane >> 4;
        const u16* xp = (const u16*)xraw;
        const u16* a0p = xp + (size_t)(r0 + lr)      * D_IN + lk * 8;
        const u16* a1p = xp + (size_t)(r0 + 16 + lr) * D_IN + lk * 8;
        const u16* b0p = Wt + (size_t)(c0 + lr)      * D_IN + lk * 8;
        const u16* b1p = Wt + (size_t)(c0 + 16 + lr) * D_IN + lk * 8;
        f32x4 acc[2][2] = {};
        #pragma unroll 4
        for (int k0 = 0; k0 < D_IN; k0 += 32) {
            bf16x8 a0 = *(const bf16x8*)(a0p + k0);
            bf16x8 a1 = *(const bf16x8*)(a1p + k0);
            bf16x8 b0 = *(const bf16x8*)(b0p + k0);
            bf16x8 b1 = *(const bf16x8*)(b1p + k0);
            acc[0][0] = __builtin_amdgcn_mfma_f32_16x16x32_bf16(a0, b0, acc[0][0], 0, 0, 0);
            acc[0][1] = __builtin_amdgcn_mfma_f32_16x16x32_bf16(a0, b1, acc[0][1], 0, 0, 0);
            acc[1][0] = __builtin_amdgcn_mfma_f32_16x16x32_bf16(a1, b0, acc[1][0], 0, 0, 0);
            acc[1][1] = __builtin_amdgcn_mfma_f32_16x16x32_bf16(a1, b1, acc[1][1], 0, 0, 0);
        }
        // C/D: col = c0+16j+(lane&15), row = r0+16i+4*(lane>>4)+reg
        #pragma unroll
        for (int i = 0; i < 2; i++) {
            #pragma unroll
            for (int reg = 0; reg < 4; reg++) {
                int r = r0 + 16 * i + 4 * lk + reg;
                float v0 = acc[i][0][reg], v1 = acc[i][1][reg];
                Wh[(size_t)r * H + c0 + lr]      = v0;
                Wh[(size_t)r * H + c0 + 16 + lr] = v1;
                __hip_bfloat16 h0 = __float2bfloat16(v0), h1 = __float2bfloat16(v1);
                Whb[(size_t)r * H + c0 + lr]      = *(u16*)&h0;
                Whb[(size_t)r * H + c0 + 16 + lr] = *(u16*)&h1;
            }
        }
        return;
    }

    // ---- fp32 VALU path ----
    int tx = tid & 15, ty = tid >> 4;
    float acc[4][4] = {};
    for (int k0 = 0; k0 < D_IN; k0 += 32) {
        {
            int r = tid >> 2, kq = (tid & 3) * 8;
            size_t base = (size_t)(m0 + r) * D_IN + k0 + kq;
            float4 f0 = *(const float4*)((const float*)xraw + base);
            float4 f1 = *(const float4*)((const float*)xraw + base + 4);
            xs[kq + 0][r] = f0.x; xs[kq + 1][r] = f0.y;
            xs[kq + 2][r] = f0.z; xs[kq + 3][r] = f0.w;
            xs[kq + 4][r] = f1.x; xs[kq + 5][r] = f1.y;
            xs[kq + 6][r] = f1.z; xs[kq + 7][r] = f1.w;
        }
        {
            int kk = tid >> 3, n8 = (tid & 7) * 8;
            size_t base = (size_t)(k0 + kk) * H + n0 + n8;
            float4 f0 = *(const float4*)((const float*)wraw + base);
            float4 f1 = *(const float4*)((const float*)wraw + base + 4);
            ws_[kk][n8+0]=f0.x; ws_[kk][n8+1]=f0.y; ws_[kk][n8+2]=f0.z; ws_[kk][n8+3]=f0.w;
            ws_[kk][n8+4]=f1.x; ws_[kk][n8+5]=f1.y; ws_[kk][n8+6]=f1.z; ws_[kk][n8+7]=f1.w;
        }
        __syncthreads();
        #pragma unroll
        for (int kk = 0; kk < 32; kk++) {
            float4 a4 = *(const float4*)&xs[kk][ty * 4];
            float4 b4 = *(const float4*)&ws_[kk][tx * 4];
            float a[4] = {a4.x, a4.y, a4.z, a4.w};
            float b[4] = {b4.x, b4.y, b4.z, b4.w};
            #pragma unroll
            for (int i = 0; i < 4; i++)
                #pragma unroll
                for (int j = 0; j < 4; j++)
                    acc[i][j] += a[i] * b[j];
        }
        __syncthreads();
    }
    #pragma unroll
    for (int i = 0; i < 4; i++) {
        float4 o = {acc[i][0], acc[i][1], acc[i][2], acc[i][3]};
        *(float4*)&Wh[(size_t)(m0 + ty*4 + i) * H + n0 + tx*4] = o;
    }
}

__global__ __launch_bounds__(256) void k_wh12(
    const float* __restrict__ Wh, const float* __restrict__ a_f,
    float* __restrict__ Wh1, float* __restrict__ Wh2)
{
    int tid = threadIdx.x;
    int wave = tid >> 6, lane = tid & 63;
    int n = blockIdx.x * 4 + wave;
    float4 v  = *(const float4*)(Wh + (size_t)n * H + lane * 4);
    float4 a1 = *(const float4*)(a_f + lane * 4);
    float4 a2 = *(const float4*)(a_f + H + lane * 4);
    float s1 = v.x*a1.x + v.y*a1.y + v.z*a1.z + v.w*a1.w;
    float s2 = v.x*a2.x + v.y*a2.y + v.z*a2.z + v.w*a2.w;
    #pragma unroll
    for (int off = 32; off; off >>= 1) {
        s1 += __shfl_xor(s1, off);
        s2 += __shfl_xor(s2, off);
    }
    if (lane == 0) { Wh1[n] = s1; Wh2[n] = s2; }
}

// one wave per row; 4 rows per block. Adjacency scan moved to k_scan —
// this kernel only does softmax + gather + cluster/GCN epilogue.
__global__ __launch_bounds__(256) void k_gat_row(
    const int* __restrict__ ncnt, const u16* __restrict__ nidx,
    const float* __restrict__ Wh, const u16* __restrict__ Whb,
    const float* __restrict__ Wh1, const float* __restrict__ Wh2,
    const float* __restrict__ Ca_f, const float* __restrict__ Wg_f,
    float* __restrict__ Gf, const void* __restrict__ adjraw,
    void* __restrict__ dout)
{
    const int tid = threadIdx.x;
    const int w = tid >> 6, lane = tid & 63;
    const int n = blockIdx.x * 4 + w;
    const int bf = detect_bf(adjraw);

    __shared__ float s_z[4][H];
    __shared__ float s_g[4][H];

    const int cnt = min(ncnt[n], MAXN);
    int i1 = 0, i2 = 0;
    if (lane < cnt)      i1 = nidx[(size_t)n * MAXN + lane];
    if (lane + 64 < cnt) i2 = nidx[(size_t)n * MAXN + lane + 64];

    // ---- softmax over <=96 entries, pure shuffles ----
    const float wh1n = Wh1[n];
    float e1 = -3e38f, e2 = -3e38f;
    if (lane < cnt)      { float v = wh1n + Wh2[i1]; e1 = v > 0.f ? v : 0.2f * v; }
    if (lane + 64 < cnt) { float v = wh1n + Wh2[i2]; e2 = v > 0.f ? v : 0.2f * v; }
    float m = fmaxf(e1, e2);
    #pragma unroll
    for (int off = 32; off; off >>= 1) m = fmaxf(m, __shfl_xor(m, off));
    float x1 = (lane < cnt)      ? expf(e1 - m) : 0.f;
    float x2 = (lane + 64 < cnt) ? expf(e2 - m) : 0.f;
    float ssum = x1 + x2;
    #pragma unroll
    for (int off = 32; off; off >>= 1) ssum += __shfl_xor(ssum, off);
    float inv = 1.f / ssum;
    float at1 = x1 * inv, at2 = x2 * inv;

    // ---- Z_0 row: gather; idx/att via shfl; x4 unrolled for MLP ----
    const int c4 = lane * 4;
    float az[4] = {0.f, 0.f, 0.f, 0.f};
    if (bf) {
        int t = 0;
        for (; t + 4 <= cnt; t += 4) {
            int ja[4]; float wa[4];
            #pragma unroll
            for (int u = 0; u < 4; u++) {
                int tt = t + u;
                ja[u] = __shfl((tt < 64) ? i1 : i2, tt & 63);
                wa[u] = __shfl((tt < 64) ? at1 : at2, tt & 63);
            }
            uint2 rr[4];
            #pragma unroll
            for (int u = 0; u < 4; u++)
                rr[u] = *(const uint2*)(Whb + (size_t)ja[u] * H + c4);
            #pragma unroll
            for (int u = 0; u < 4; u++) {
                az[0] += wa[u] * bf2f(rr[u].x & 0xFFFFu);
                az[1] += wa[u] * bf2f(rr[u].x >> 16);
                az[2] += wa[u] * bf2f(rr[u].y & 0xFFFFu);
                az[3] += wa[u] * bf2f(rr[u].y >> 16);
            }
        }
        for (; t < cnt; t++) {
            int   it_ = __shfl((t < 64) ? i1 : i2, t & 63);
            float wt_ = __shfl((t < 64) ? at1 : at2, t & 63);
            uint2 r = *(const uint2*)(Whb + (size_t)it_ * H + c4);
            az[0] += wt_ * bf2f(r.x & 0xFFFFu);
            az[1] += wt_ * bf2f(r.x >> 16);
            az[2] += wt_ * bf2f(r.y & 0xFFFFu);
            az[3] += wt_ * bf2f(r.y >> 16);
        }
    } else {
        int t = 0;
        for (; t + 4 <= cnt; t += 4) {
            int ja[4]; float wa[4];
            #pragma unroll
            for (int u = 0; u < 4; u++) {
                int tt = t + u;
                ja[u] = __shfl((tt < 64) ? i1 : i2, tt & 63);
                wa[u] = __shfl((tt < 64) ? at1 : at2, tt & 63);
            }
            float4 rr[4];
            #pragma unroll
            for (int u = 0; u < 4; u++)
                rr[u] = *(const float4*)(Wh + (size_t)ja[u] * H + c4);
            #pragma unroll
            for (int u = 0; u < 4; u++) {
                az[0] += wa[u] * rr[u].x; az[1] += wa[u] * rr[u].y;
                az[2] += wa[u] * rr[u].z; az[3] += wa[u] * rr[u].w;
            }
        }
        for (; t < cnt; t++) {
            int   it_ = __shfl((t < 64) ? i1 : i2, t & 63);
            float wt_ = __shfl((t < 64) ? at1 : at2, t & 63);
            float4 v = *(const float4*)(Wh + (size_t)it_ * H + c4);
            az[0] += wt_ * v.x; az[1] += wt_ * v.y;
            az[2] += wt_ * v.z; az[3] += wt_ * v.w;
        }
    }
    #pragma unroll
    for (int q = 0; q < 4; q++) {
        float z = az[q];
        store_out(dout, bf, (size_t)Z0_OFF + (size_t)n * H + c4 + q, z);
        s_z[w][c4 + q] = z;
        s_g[w][c4 + q] = z > 0.f ? z : expf(z) - 1.f;
    }
    __syncthreads();

    // ---- cluster score: lane = k + 16*g, g covers 64 channels ----
    {
        int k = lane & 15, g = lane >> 4;
        const float* cz = &s_z[w][0];
        const float* ck = Ca_f + (size_t)k * H;
        float d2 = 0.f;
        #pragma unroll 8
        for (int i = 0; i < 64; i++) {
            int ch = g * 64 + ((i + g * 16) & 63);
            float d = cz[ch] - ck[ch];
            d2 += d * d;
        }
        d2 += __shfl_xor(d2, 16);
        d2 += __shfl_xor(d2, 32);
        float sc = expf(-sqrtf(d2)) + 1e-10f;
        float tot = sc;
        tot += __shfl_xor(tot, 1); tot += __shfl_xor(tot, 2);
        tot += __shfl_xor(tot, 4); tot += __shfl_xor(tot, 8);
        if (lane < 16)
            store_out(dout, bf, (size_t)SC_OFF + (size_t)n * K_CL + lane, sc / tot);
    }

    // ---- GCN projection: lane = o + 16*g ----
    {
        int o = lane & 15, g = lane >> 4;
        const float* cg = &s_g[w][0];
        float p = 0.f;
        #pragma unroll 8
        for (int i = 0; i < 64; i++) {
            int ch = g * 64 + ((i + g * 16) & 63);
            p += cg[ch] * Wg_f[(size_t)ch * D_OUT + o];
        }
        p += __shfl_xor(p, 16);
        p += __shfl_xor(p, 32);
        if (lane < 16) Gf[(size_t)n * D_OUT + lane] = p;
    }
}

__global__ __launch_bounds__(256) void k_f1(
    const int* __restrict__ nbr_cnt, const u16* __restrict__ nbr_idx,
    const float* __restrict__ Gf, const void* __restrict__ adj,
    void* __restrict__ dout)
{
    int tid = threadIdx.x;
    int bf = detect_bf(adj);
    int r = tid >> 4, o = tid & 15;
    int n = blockIdx.x * 16 + r;
    int cnt = min(nbr_cnt[n], MAXN);
    const u16* idx = nbr_idx + (size_t)n * MAXN;
    float acc = 0.f;
    int t = 0;
    for (; t + 4 <= cnt; t += 4) {
        int i0 = idx[t], i1 = idx[t+1], i2 = idx[t+2], i3 = idx[t+3];
        float g0 = Gf[(size_t)i0 * D_OUT + o];
        float g1 = Gf[(size_t)i1 * D_OUT + o];
        float g2 = Gf[(size_t)i2 * D_OUT + o];
        float g3 = Gf[(size_t)i3 * D_OUT + o];
        acc += g0; acc += g1; acc += g2; acc += g3;
    }
    for (; t < cnt; t++)
        acc += Gf[(size_t)idx[t] * D_OUT + o];
    acc = fmaxf(acc, 0.f);
    store_out(dout, bf, (size_t)OUT_OFF + (size_t)n * D_OUT + o, acc);
    store_out(dout, bf, (size_t)Z1_OFF  + (size_t)n * D_OUT + o, acc);
}

extern "C" void kernel_launch(void* const* d_in, const int* in_sizes, int n_in,
                              void* d_out, int out_size, void* d_ws, size_t ws_size,
                              hipStream_t stream) {
    const void* x    = d_in[0];
    const void* adj  = d_in[1];
    const void* C_a  = d_in[2];
    const void* W    = d_in[3];
    const void* av   = d_in[4];
    const void* Wgcn = d_in[5];

    char* wsp = (char*)d_ws;
    float* Wh   = (float*)wsp;                 wsp += (size_t)N_NODES * H * 4;
    u16*   Whb  = (u16*)wsp;                   wsp += (size_t)N_NODES * H * 2;
    float* Wh1  = (float*)wsp;                 wsp += (size_t)N_NODES * 4;
    float* Wh2  = (float*)wsp;                 wsp += (size_t)N_NODES * 4;
    float* Gf   = (float*)wsp;                 wsp += (size_t)N_NODES * D_OUT * 4;
    int*   ncnt = (int*)wsp;                   wsp += (size_t)N_NODES * 4;
    u16*   nidx = (u16*)wsp;                   wsp += (size_t)N_NODES * MAXN * 2;
    float* a_f  = (float*)wsp;                 wsp += 2 * H * 4;
    float* Ca_f = (float*)wsp;                 wsp += (size_t)K_CL * H * 4;
    float* Wg_f = (float*)wsp;                 wsp += (size_t)H * D_OUT * 4;
    u16*   Wt   = (u16*)wsp;                   wsp += (size_t)H * D_IN * 2;

    hipMemsetAsync(ncnt, 0, (size_t)N_NODES * 4, stream);
    k_prep    <<<66, 256, 0, stream>>>(W, av, C_a, Wgcn, adj, Wt, a_f, Ca_f, Wg_f);
    k_scan    <<<2048, 256, 0, stream>>>(adj, ncnt, nidx);
    k_gemm_wh <<<512, 256, 0, stream>>>(x, W, Wt, adj, Wh, Whb);
    k_wh12    <<<N_NODES / 4, 256, 0, stream>>>(Wh, a_f, Wh1, Wh2);
    k_gat_row <<<N_NODES / 4, 256, 0, stream>>>(ncnt, nidx, Wh, Whb, Wh1, Wh2,
                                                Ca_f, Wg_f, Gf, adj, d_out);
    k_f1      <<<N_NODES / 16, 256, 0, stream>>>(ncnt, nidx, Gf, adj, d_out);
}

// Round 5
// 442.837 us; speedup vs baseline: 1.1461x; 1.1461x over previous
//
#include <hip/hip_runtime.h>
#include <hip/hip_bf16.h>

#define N_NODES 8192
#define D_IN    512
#define H       256
#define D_OUT   16
#define K_CL    16
#define MAXN    96

// flat output element offsets (dtype-agnostic): output | Z_1 | Z_0 | score
#define OUT_OFF 0
#define Z1_OFF  131072
#define Z0_OFF  262144
#define SC_OFF  2359296

typedef unsigned int   u32;
typedef unsigned short u16;
typedef __attribute__((ext_vector_type(8))) short bf16x8;
typedef __attribute__((ext_vector_type(4))) float f32x4;

__device__ __forceinline__ float load_in(const void* p, int bf, size_t idx) {
    if (bf) { u32 w = ((const u16*)p)[idx]; return __uint_as_float(w << 16); }
    return ((const float*)p)[idx];
}
__device__ __forceinline__ void store_out(void* p, int bf, size_t idx, float v) {
    if (bf) ((__hip_bfloat16*)p)[idx] = __float2bfloat16(v);
    else    ((float*)p)[idx] = v;
}
// adj = max(adj, I) guarantees adj[0][0] == 1.0.
// fp32: word0 == 0x3F800000 exactly. bf16: word0 == 0x00003F80 or 0x3F803F80.
__device__ __forceinline__ int detect_bf(const void* adj) {
    return ((const u32*)adj)[0] != 0x3F800000u;
}
__device__ __forceinline__ float bf2f(u32 h) { return __uint_as_float(h << 16); }

// merged prep: blocks 0..31 transpose W -> Wt (bf16 [H][D_IN]);
// blocks 32..65 copy small params AND zero Wh1/Wh2 (accumulated by k_gemm_wh).
__global__ __launch_bounds__(256) void k_prep(
    const void* __restrict__ wraw, const void* av, const void* C_a, const void* Wgcn,
    const void* __restrict__ adj,
    u16* __restrict__ Wt, float* a_f, float* Ca_f, float* Wg_f,
    float* __restrict__ Wh1, float* __restrict__ Wh2)
{
    int bf = detect_bf(adj);
    int b = blockIdx.x, tid = threadIdx.x;
    if (b >= 32) {
        int i = (b - 32) * 256 + tid;
        if (i < 512)        a_f[i]         = load_in(av,   bf, i);
        else if (i < 4608)  Ca_f[i - 512]  = load_in(C_a,  bf, i - 512);
        else if (i < 8704)  Wg_f[i - 4608] = load_in(Wgcn, bf, i - 4608);
        if (i < N_NODES) { Wh1[i] = 0.f; Wh2[i] = 0.f; }
        return;
    }
    __shared__ float tile[64][65];
    int k0 = (b >> 2) * 64, h0 = (b & 3) * 64;
    int hh = tid & 63, kk = tid >> 6;
    #pragma unroll
    for (int p = 0; p < 16; p++) {
        int k = kk * 16 + p;
        tile[k][hh] = load_in(wraw, bf, (size_t)(k0 + k) * H + h0 + hh);
    }
    __syncthreads();
    int kc = tid & 63, hr = tid >> 6;
    #pragma unroll
    for (int p = 0; p < 16; p++) {
        int h = hr * 16 + p;
        __hip_bfloat16 bb = __float2bfloat16(tile[kc][h]);
        Wt[(size_t)(h0 + h) * D_IN + k0 + kc] = *(u16*)&bb;
    }
}

// GEMM Wh = x @ W with fused Wh1/Wh2 = Wh @ a[:H], Wh @ a[H:] partial sums
// (shuffle-reduce per 64-col tile, atomicAdd; Wh1/Wh2 zeroed in k_prep).
__global__ __launch_bounds__(256) void k_gemm_wh(
    const void* __restrict__ xraw, const void* __restrict__ wraw,
    const u16* __restrict__ Wt, const void* __restrict__ adj,
    const float* __restrict__ a_f,
    float* __restrict__ Wh, float* __restrict__ Wh1, float* __restrict__ Wh2)
{
    int bf = detect_bf(adj);
    __shared__ float xs[32][68];
    __shared__ float ws_[32][68];
    int tid = threadIdx.x;
    int bm = blockIdx.x >> 2, bn = blockIdx.x & 3;
    int m0 = bm * 64, n0 = bn * 64;

    if (bf) {
        // ---- bf16 MFMA path: 64x64 tile, 4 waves, each wave 32x32 ----
        int wave = tid >> 6, lane = tid & 63;
        int wr = wave >> 1, wc = wave & 1;
        int r0 = m0 + wr * 32, c0 = n0 + wc * 32;
        int lr = lane & 15, lk = lane >> 4;
        const u16* xp = (const u16*)xraw;
        const u16* a0p = xp + (size_t)(r0 + lr)      * D_IN + lk * 8;
        const u16* a1p = xp + (size_t)(r0 + 16 + lr) * D_IN + lk * 8;
        const u16* b0p = Wt + (size_t)(c0 + lr)      * D_IN + lk * 8;
        const u16* b1p = Wt + (size_t)(c0 + 16 + lr) * D_IN + lk * 8;
        f32x4 acc[2][2] = {};
        #pragma unroll 4
        for (int k0 = 0; k0 < D_IN; k0 += 32) {
            bf16x8 a0 = *(const bf16x8*)(a0p + k0);
            bf16x8 a1 = *(const bf16x8*)(a1p + k0);
            bf16x8 b0 = *(const bf16x8*)(b0p + k0);
            bf16x8 b1 = *(const bf16x8*)(b1p + k0);
            acc[0][0] = __builtin_amdgcn_mfma_f32_16x16x32_bf16(a0, b0, acc[0][0], 0, 0, 0);
            acc[0][1] = __builtin_amdgcn_mfma_f32_16x16x32_bf16(a0, b1, acc[0][1], 0, 0, 0);
            acc[1][0] = __builtin_amdgcn_mfma_f32_16x16x32_bf16(a1, b0, acc[1][0], 0, 0, 0);
            acc[1][1] = __builtin_amdgcn_mfma_f32_16x16x32_bf16(a1, b1, acc[1][1], 0, 0, 0);
        }
        // C/D: col = c0+16j+(lane&15), row = r0+16i+4*(lane>>4)+reg
        float a1v0 = a_f[c0 + lr],     a1v1 = a_f[c0 + 16 + lr];
        float a2v0 = a_f[H + c0 + lr], a2v1 = a_f[H + c0 + 16 + lr];
        #pragma unroll
        for (int i = 0; i < 2; i++) {
            #pragma unroll
            for (int reg = 0; reg < 4; reg++) {
                int r = r0 + 16 * i + 4 * lk + reg;
                float v0 = acc[i][0][reg], v1 = acc[i][1][reg];
                Wh[(size_t)r * H + c0 + lr]      = v0;
                Wh[(size_t)r * H + c0 + 16 + lr] = v1;
                // fused Wh@a partial over this 32-col slice
                float s1 = a1v0 * v0 + a1v1 * v1;
                float s2 = a2v0 * v0 + a2v1 * v1;
                #pragma unroll
                for (int off = 8; off; off >>= 1) {
                    s1 += __shfl_xor(s1, off);
                    s2 += __shfl_xor(s2, off);
                }
                if (lr == 0) {
                    atomicAdd(&Wh1[r], s1);
                    atomicAdd(&Wh2[r], s2);
                }
            }
        }
        return;
    }

    // ---- fp32 VALU path ----
    int tx = tid & 15, ty = tid >> 4;
    float acc[4][4] = {};
    for (int k0 = 0; k0 < D_IN; k0 += 32) {
        {
            int r = tid >> 2, kq = (tid & 3) * 8;
            size_t base = (size_t)(m0 + r) * D_IN + k0 + kq;
            float4 f0 = *(const float4*)((const float*)xraw + base);
            float4 f1 = *(const float4*)((const float*)xraw + base + 4);
            xs[kq + 0][r] = f0.x; xs[kq + 1][r] = f0.y;
            xs[kq + 2][r] = f0.z; xs[kq + 3][r] = f0.w;
            xs[kq + 4][r] = f1.x; xs[kq + 5][r] = f1.y;
            xs[kq + 6][r] = f1.z; xs[kq + 7][r] = f1.w;
        }
        {
            int kk = tid >> 3, n8 = (tid & 7) * 8;
            size_t base = (size_t)(k0 + kk) * H + n0 + n8;
            float4 f0 = *(const float4*)((const float*)wraw + base);
            float4 f1 = *(const float4*)((const float*)wraw + base + 4);
            ws_[kk][n8+0]=f0.x; ws_[kk][n8+1]=f0.y; ws_[kk][n8+2]=f0.z; ws_[kk][n8+3]=f0.w;
            ws_[kk][n8+4]=f1.x; ws_[kk][n8+5]=f1.y; ws_[kk][n8+6]=f1.z; ws_[kk][n8+7]=f1.w;
        }
        __syncthreads();
        #pragma unroll
        for (int kk = 0; kk < 32; kk++) {
            float4 a4 = *(const float4*)&xs[kk][ty * 4];
            float4 b4 = *(const float4*)&ws_[kk][tx * 4];
            float a[4] = {a4.x, a4.y, a4.z, a4.w};
            float b[4] = {b4.x, b4.y, b4.z, b4.w};
            #pragma unroll
            for (int i = 0; i < 4; i++)
                #pragma unroll
                for (int j = 0; j < 4; j++)
                    acc[i][j] += a[i] * b[j];
        }
        __syncthreads();
    }
    float4 av1 = *(const float4*)(a_f + n0 + tx * 4);
    float4 av2 = *(const float4*)(a_f + H + n0 + tx * 4);
    #pragma unroll
    for (int i = 0; i < 4; i++) {
        float4 o = {acc[i][0], acc[i][1], acc[i][2], acc[i][3]};
        *(float4*)&Wh[(size_t)(m0 + ty*4 + i) * H + n0 + tx*4] = o;
        float s1 = o.x*av1.x + o.y*av1.y + o.z*av1.z + o.w*av1.w;
        float s2 = o.x*av2.x + o.y*av2.y + o.z*av2.z + o.w*av2.w;
        #pragma unroll
        for (int off = 8; off; off >>= 1) {
            s1 += __shfl_xor(s1, off);
            s2 += __shfl_xor(s2, off);
        }
        if (tx == 0) {
            atomicAdd(&Wh1[m0 + ty*4 + i], s1);
            atomicAdd(&Wh2[m0 + ty*4 + i], s2);
        }
    }
}

// round-1 champion structure: one block (256 thr) per row, fused scan.
__global__ __launch_bounds__(256) void k_gat_row(
    const void* __restrict__ adjraw,
    const float* __restrict__ Wh,
    const float* __restrict__ Wh1, const float* __restrict__ Wh2,
    const float* __restrict__ Ca_f, const float* __restrict__ Wg_f,
    float* __restrict__ Gf,
    int* __restrict__ nbr_cnt, u16* __restrict__ nbr_idx,
    void* __restrict__ dout)
{
    const int n = blockIdx.x;
    const int tid = threadIdx.x;
    const int bf = detect_bf(adjraw);
    __shared__ int   s_cnt;
    __shared__ int   s_idx[MAXN];
    __shared__ float s_att[MAXN];
    __shared__ float s_z[H];
    __shared__ float s_g[H];
    __shared__ float s_red[256];
    __shared__ float s_sc[16];

    if (tid == 0) s_cnt = 0;
    __syncthreads();

    if (bf) {
        const u16* arow = (const u16*)adjraw + (size_t)n * N_NODES;
        #pragma unroll
        for (int it = 0; it < 4; it++) {
            int base = it * 2048 + tid * 8;
            uint4 raw = *(const uint4*)(arow + base);
            u32 rw[4] = {raw.x, raw.y, raw.z, raw.w};
            #pragma unroll
            for (int q = 0; q < 4; q++) {
                #pragma unroll
                for (int hh = 0; hh < 2; hh++) {
                    u32 u = (rw[q] >> (16 * hh)) & 0xFFFFu;
                    if (bf2f(u) > 0.f) {
                        int p = atomicAdd(&s_cnt, 1);
                        if (p < MAXN) s_idx[p] = base + q * 2 + hh;
                    }
                }
            }
        }
    } else {
        const float* arow = (const float*)adjraw + (size_t)n * N_NODES;
        #pragma unroll
        for (int it = 0; it < 8; it++) {
            int base = it * 1024 + tid * 4;
            float4 v = *(const float4*)(arow + base);
            float vv[4] = {v.x, v.y, v.z, v.w};
            #pragma unroll
            for (int q = 0; q < 4; q++) {
                if (vv[q] > 0.f) {
                    int p = atomicAdd(&s_cnt, 1);
                    if (p < MAXN) s_idx[p] = base + q;
                }
            }
        }
    }
    __syncthreads();
    const int cnt = min(s_cnt, MAXN);
    if (tid == 0) nbr_cnt[n] = cnt;
    if (tid < cnt) nbr_idx[(size_t)n * MAXN + tid] = (u16)s_idx[tid];

    // --- softmax over cnt (<=96) entries: wave shuffle reductions ---
    float e = 0.f;
    if (tid < cnt) {
        float v = Wh1[n] + Wh2[s_idx[tid]];
        e = v > 0.f ? v : 0.2f * v;
    }
    int lane = tid & 63, wv = tid >> 6;
    float vmax = (tid < cnt) ? e : -3e38f;
    #pragma unroll
    for (int off = 32; off; off >>= 1) vmax = fmaxf(vmax, __shfl_xor(vmax, off));
    if (lane == 0) s_red[wv] = vmax;
    __syncthreads();
    float m = fmaxf(fmaxf(s_red[0], s_red[1]), fmaxf(s_red[2], s_red[3]));
    float wexp = (tid < cnt) ? expf(e - m) : 0.f;
    float ssum = wexp;
    #pragma unroll
    for (int off = 32; off; off >>= 1) ssum += __shfl_xor(ssum, off);
    if (lane == 0) s_red[8 + wv] = ssum;
    __syncthreads();
    float denom = s_red[8] + s_red[9] + s_red[10] + s_red[11];
    if (tid < cnt) s_att[tid] = wexp / denom;
    __syncthreads();

    // --- Z_0 row: att @ Wh, gather unrolled x4 for memory-level parallelism ---
    float acc = 0.f;
    {
        int t = 0;
        for (; t + 4 <= cnt; t += 4) {
            int i0 = s_idx[t], i1 = s_idx[t+1], i2 = s_idx[t+2], i3 = s_idx[t+3];
            float w0 = s_att[t], w1 = s_att[t+1], w2 = s_att[t+2], w3 = s_att[t+3];
            float x0 = Wh[(size_t)i0 * H + tid];
            float x1 = Wh[(size_t)i1 * H + tid];
            float x2 = Wh[(size_t)i2 * H + tid];
            float x3 = Wh[(size_t)i3 * H + tid];
            acc += w0 * x0; acc += w1 * x1; acc += w2 * x2; acc += w3 * x3;
        }
        for (; t < cnt; t++)
            acc += s_att[t] * Wh[(size_t)s_idx[t] * H + tid];
    }
    s_z[tid] = acc;
    store_out(dout, bf, (size_t)Z0_OFF + (size_t)n * H + tid, acc);
    s_g[tid] = acc > 0.f ? acc : expf(acc) - 1.f;
    __syncthreads();

    {
        int k = tid & 15, hb = (tid >> 4) * 16;
        float p = 0.f;
        #pragma unroll
        for (int i = 0; i < 16; i++) {
            float d = s_z[hb + i] - Ca_f[(size_t)k * H + hb + i];
            p += d * d;
        }
        s_red[tid] = p;
    }
    __syncthreads();
    if (tid < 16) {
        float d2 = 0.f;
        #pragma unroll
        for (int q = 0; q < 16; q++) d2 += s_red[q * 16 + tid];
        s_sc[tid] = expf(-sqrtf(d2)) + 1e-10f;
    }
    __syncthreads();
    if (tid < 16) {
        float tot = 0.f;
        #pragma unroll
        for (int q = 0; q < 16; q++) tot += s_sc[q];
        store_out(dout, bf, (size_t)SC_OFF + (size_t)n * K_CL + tid, s_sc[tid] / tot);
    }
    __syncthreads();

    {
        int o = tid & 15, hb = (tid >> 4) * 16;
        float p = 0.f;
        #pragma unroll
        for (int i = 0; i < 16; i++)
            p += s_g[hb + i] * Wg_f[(size_t)(hb + i) * D_OUT + o];
        s_red[tid] = p;
    }
    __syncthreads();
    if (tid < 16) {
        float g2 = 0.f;
        #pragma unroll
        for (int q = 0; q < 16; q++) g2 += s_red[q * 16 + tid];
        Gf[(size_t)n * D_OUT + tid] = g2;
    }
}

__global__ __launch_bounds__(256) void k_f1(
    const int* __restrict__ nbr_cnt, const u16* __restrict__ nbr_idx,
    const float* __restrict__ Gf, const void* __restrict__ adj,
    void* __restrict__ dout)
{
    int tid = threadIdx.x;
    int bf = detect_bf(adj);
    int r = tid >> 4, o = tid & 15;
    int n = blockIdx.x * 16 + r;
    int cnt = min(nbr_cnt[n], MAXN);
    const u16* idx = nbr_idx + (size_t)n * MAXN;
    float acc = 0.f;
    int t = 0;
    for (; t + 4 <= cnt; t += 4) {
        int i0 = idx[t], i1 = idx[t+1], i2 = idx[t+2], i3 = idx[t+3];
        float g0 = Gf[(size_t)i0 * D_OUT + o];
        float g1 = Gf[(size_t)i1 * D_OUT + o];
        float g2 = Gf[(size_t)i2 * D_OUT + o];
        float g3 = Gf[(size_t)i3 * D_OUT + o];
        acc += g0; acc += g1; acc += g2; acc += g3;
    }
    for (; t < cnt; t++)
        acc += Gf[(size_t)idx[t] * D_OUT + o];
    acc = fmaxf(acc, 0.f);
    store_out(dout, bf, (size_t)OUT_OFF + (size_t)n * D_OUT + o, acc);
    store_out(dout, bf, (size_t)Z1_OFF  + (size_t)n * D_OUT + o, acc);
}

extern "C" void kernel_launch(void* const* d_in, const int* in_sizes, int n_in,
                              void* d_out, int out_size, void* d_ws, size_t ws_size,
                              hipStream_t stream) {
    const void* x    = d_in[0];
    const void* adj  = d_in[1];
    const void* C_a  = d_in[2];
    const void* W    = d_in[3];
    const void* av   = d_in[4];
    const void* Wgcn = d_in[5];

    char* wsp = (char*)d_ws;
    float* Wh   = (float*)wsp;                 wsp += (size_t)N_NODES * H * 4;
    float* Wh1  = (float*)wsp;                 wsp += (size_t)N_NODES * 4;
    float* Wh2  = (float*)wsp;                 wsp += (size_t)N_NODES * 4;
    float* Gf   = (float*)wsp;                 wsp += (size_t)N_NODES * D_OUT * 4;
    int*   ncnt = (int*)wsp;                   wsp += (size_t)N_NODES * 4;
    u16*   nidx = (u16*)wsp;                   wsp += (size_t)N_NODES * MAXN * 2;
    float* a_f  = (float*)wsp;                 wsp += 2 * H * 4;
    float* Ca_f = (float*)wsp;                 wsp += (size_t)K_CL * H * 4;
    float* Wg_f = (float*)wsp;                 wsp += (size_t)H * D_OUT * 4;
    u16*   Wt   = (u16*)wsp;                   wsp += (size_t)H * D_IN * 2;

    k_prep    <<<66, 256, 0, stream>>>(W, av, C_a, Wgcn, adj, Wt, a_f, Ca_f, Wg_f,
                                       Wh1, Wh2);
    k_gemm_wh <<<512, 256, 0, stream>>>(x, W, Wt, adj, a_f, Wh, Wh1, Wh2);
    k_gat_row <<<N_NODES, 256, 0, stream>>>(adj, Wh, Wh1, Wh2, Ca_f, Wg_f,
                                            Gf, ncnt, nidx, d_out);
    k_f1      <<<N_NODES / 16, 256, 0, stream>>>(ncnt, nidx, Gf, adj, d_out);
}

// Round 6
// 429.351 us; speedup vs baseline: 1.1821x; 1.0314x over previous
//
#include <hip/hip_runtime.h>
#include <hip/hip_bf16.h>

#define N_NODES 8192
#define D_IN    512
#define H       256
#define D_OUT   16
#define K_CL    16
#define MAXN    96

// flat output element offsets (dtype-agnostic): output | Z_1 | Z_0 | score
#define OUT_OFF 0
#define Z1_OFF  131072
#define Z0_OFF  262144
#define SC_OFF  2359296

typedef unsigned int   u32;
typedef unsigned short u16;
typedef __attribute__((ext_vector_type(8))) short bf16x8;
typedef __attribute__((ext_vector_type(4))) float f32x4;
typedef __attribute__((ext_vector_type(4))) u32   u32x4;

__device__ __forceinline__ float load_in(const void* p, int bf, size_t idx) {
    if (bf) { u32 w = ((const u16*)p)[idx]; return __uint_as_float(w << 16); }
    return ((const float*)p)[idx];
}
__device__ __forceinline__ void store_out(void* p, int bf, size_t idx, float v) {
    if (bf) ((__hip_bfloat16*)p)[idx] = __float2bfloat16(v);
    else    ((float*)p)[idx] = v;
}
// adj = max(adj, I) guarantees adj[0][0] == 1.0.
// fp32: word0 == 0x3F800000 exactly. bf16: word0 == 0x00003F80 or 0x3F803F80.
__device__ __forceinline__ int detect_bf(const void* adj) {
    return ((const u32*)adj)[0] != 0x3F800000u;
}
__device__ __forceinline__ float bf2f(u32 h) { return __uint_as_float(h << 16); }

// merged prep: blocks 0..31 transpose W -> Wt (bf16 [H][D_IN]);
// blocks 32..65 copy small params AND zero Wh1/Wh2 (accumulated by k_gemm_wh).
__global__ __launch_bounds__(256) void k_prep(
    const void* __restrict__ wraw, const void* av, const void* C_a, const void* Wgcn,
    const void* __restrict__ adj,
    u16* __restrict__ Wt, float* a_f, float* Ca_f, float* Wg_f,
    float* __restrict__ Wh1, float* __restrict__ Wh2)
{
    int bf = detect_bf(adj);
    int b = blockIdx.x, tid = threadIdx.x;
    if (b >= 32) {
        int i = (b - 32) * 256 + tid;
        if (i < 512)        a_f[i]         = load_in(av,   bf, i);
        else if (i < 4608)  Ca_f[i - 512]  = load_in(C_a,  bf, i - 512);
        else if (i < 8704)  Wg_f[i - 4608] = load_in(Wgcn, bf, i - 4608);
        if (i < N_NODES) { Wh1[i] = 0.f; Wh2[i] = 0.f; }
        return;
    }
    __shared__ float tile[64][65];
    int k0 = (b >> 2) * 64, h0 = (b & 3) * 64;
    int hh = tid & 63, kk = tid >> 6;
    #pragma unroll
    for (int p = 0; p < 16; p++) {
        int k = kk * 16 + p;
        tile[k][hh] = load_in(wraw, bf, (size_t)(k0 + k) * H + h0 + hh);
    }
    __syncthreads();
    int kc = tid & 63, hr = tid >> 6;
    #pragma unroll
    for (int p = 0; p < 16; p++) {
        int h = hr * 16 + p;
        __hip_bfloat16 bb = __float2bfloat16(tile[kc][h]);
        Wt[(size_t)(h0 + h) * D_IN + k0 + kc] = *(u16*)&bb;
    }
}

// GEMM Wh = x @ W with fused Wh1/Wh2 = Wh @ a[:H], Wh @ a[H:] partial sums
// (shuffle-reduce per 64-col tile, atomicAdd; Wh1/Wh2 zeroed in k_prep).
__global__ __launch_bounds__(256) void k_gemm_wh(
    const void* __restrict__ xraw, const void* __restrict__ wraw,
    const u16* __restrict__ Wt, const void* __restrict__ adj,
    const float* __restrict__ a_f,
    float* __restrict__ Wh, float* __restrict__ Wh1, float* __restrict__ Wh2)
{
    int bf = detect_bf(adj);
    __shared__ float xs[32][68];
    __shared__ float ws_[32][68];
    int tid = threadIdx.x;
    int bm = blockIdx.x >> 2, bn = blockIdx.x & 3;
    int m0 = bm * 64, n0 = bn * 64;

    if (bf) {
        // ---- bf16 MFMA path: 64x64 tile, 4 waves, each wave 32x32 ----
        int wave = tid >> 6, lane = tid & 63;
        int wr = wave >> 1, wc = wave & 1;
        int r0 = m0 + wr * 32, c0 = n0 + wc * 32;
        int lr = lane & 15, lk = lane >> 4;
        const u16* xp = (const u16*)xraw;
        const u16* a0p = xp + (size_t)(r0 + lr)      * D_IN + lk * 8;
        const u16* a1p = xp + (size_t)(r0 + 16 + lr) * D_IN + lk * 8;
        const u16* b0p = Wt + (size_t)(c0 + lr)      * D_IN + lk * 8;
        const u16* b1p = Wt + (size_t)(c0 + 16 + lr) * D_IN + lk * 8;
        f32x4 acc[2][2] = {};
        #pragma unroll 4
        for (int k0 = 0; k0 < D_IN; k0 += 32) {
            bf16x8 a0 = *(const bf16x8*)(a0p + k0);
            bf16x8 a1 = *(const bf16x8*)(a1p + k0);
            bf16x8 b0 = *(const bf16x8*)(b0p + k0);
            bf16x8 b1 = *(const bf16x8*)(b1p + k0);
            acc[0][0] = __builtin_amdgcn_mfma_f32_16x16x32_bf16(a0, b0, acc[0][0], 0, 0, 0);
            acc[0][1] = __builtin_amdgcn_mfma_f32_16x16x32_bf16(a0, b1, acc[0][1], 0, 0, 0);
            acc[1][0] = __builtin_amdgcn_mfma_f32_16x16x32_bf16(a1, b0, acc[1][0], 0, 0, 0);
            acc[1][1] = __builtin_amdgcn_mfma_f32_16x16x32_bf16(a1, b1, acc[1][1], 0, 0, 0);
        }
        // C/D: col = c0+16j+(lane&15), row = r0+16i+4*(lane>>4)+reg
        float a1v0 = a_f[c0 + lr],     a1v1 = a_f[c0 + 16 + lr];
        float a2v0 = a_f[H + c0 + lr], a2v1 = a_f[H + c0 + 16 + lr];
        #pragma unroll
        for (int i = 0; i < 2; i++) {
            #pragma unroll
            for (int reg = 0; reg < 4; reg++) {
                int r = r0 + 16 * i + 4 * lk + reg;
                float v0 = acc[i][0][reg], v1 = acc[i][1][reg];
                Wh[(size_t)r * H + c0 + lr]      = v0;
                Wh[(size_t)r * H + c0 + 16 + lr] = v1;
                // fused Wh@a partial over this 32-col slice
                float s1 = a1v0 * v0 + a1v1 * v1;
                float s2 = a2v0 * v0 + a2v1 * v1;
                #pragma unroll
                for (int off = 8; off; off >>= 1) {
                    s1 += __shfl_xor(s1, off);
                    s2 += __shfl_xor(s2, off);
                }
                if (lr == 0) {
                    atomicAdd(&Wh1[r], s1);
                    atomicAdd(&Wh2[r], s2);
                }
            }
        }
        return;
    }

    // ---- fp32 VALU path ----
    int tx = tid & 15, ty = tid >> 4;
    float acc[4][4] = {};
    for (int k0 = 0; k0 < D_IN; k0 += 32) {
        {
            int r = tid >> 2, kq = (tid & 3) * 8;
            size_t base = (size_t)(m0 + r) * D_IN + k0 + kq;
            float4 f0 = *(const float4*)((const float*)xraw + base);
            float4 f1 = *(const float4*)((const float*)xraw + base + 4);
            xs[kq + 0][r] = f0.x; xs[kq + 1][r] = f0.y;
            xs[kq + 2][r] = f0.z; xs[kq + 3][r] = f0.w;
            xs[kq + 4][r] = f1.x; xs[kq + 5][r] = f1.y;
            xs[kq + 6][r] = f1.z; xs[kq + 7][r] = f1.w;
        }
        {
            int kk = tid >> 3, n8 = (tid & 7) * 8;
            size_t base = (size_t)(k0 + kk) * H + n0 + n8;
            float4 f0 = *(const float4*)((const float*)wraw + base);
            float4 f1 = *(const float4*)((const float*)wraw + base + 4);
            ws_[kk][n8+0]=f0.x; ws_[kk][n8+1]=f0.y; ws_[kk][n8+2]=f0.z; ws_[kk][n8+3]=f0.w;
            ws_[kk][n8+4]=f1.x; ws_[kk][n8+5]=f1.y; ws_[kk][n8+6]=f1.z; ws_[kk][n8+7]=f1.w;
        }
        __syncthreads();
        #pragma unroll
        for (int kk = 0; kk < 32; kk++) {
            float4 a4 = *(const float4*)&xs[kk][ty * 4];
            float4 b4 = *(const float4*)&ws_[kk][tx * 4];
            float a[4] = {a4.x, a4.y, a4.z, a4.w};
            float b[4] = {b4.x, b4.y, b4.z, b4.w};
            #pragma unroll
            for (int i = 0; i < 4; i++)
                #pragma unroll
                for (int j = 0; j < 4; j++)
                    acc[i][j] += a[i] * b[j];
        }
        __syncthreads();
    }
    float4 av1 = *(const float4*)(a_f + n0 + tx * 4);
    float4 av2 = *(const float4*)(a_f + H + n0 + tx * 4);
    #pragma unroll
    for (int i = 0; i < 4; i++) {
        float4 o = {acc[i][0], acc[i][1], acc[i][2], acc[i][3]};
        *(float4*)&Wh[(size_t)(m0 + ty*4 + i) * H + n0 + tx*4] = o;
        float s1 = o.x*av1.x + o.y*av1.y + o.z*av1.z + o.w*av1.w;
        float s2 = o.x*av2.x + o.y*av2.y + o.z*av2.z + o.w*av2.w;
        #pragma unroll
        for (int off = 8; off; off >>= 1) {
            s1 += __shfl_xor(s1, off);
            s2 += __shfl_xor(s2, off);
        }
        if (tx == 0) {
            atomicAdd(&Wh1[m0 + ty*4 + i], s1);
            atomicAdd(&Wh2[m0 + ty*4 + i], s2);
        }
    }
}

// block-per-row champion structure. Scan loads forced into a single asm clause:
// 4 (bf16) / 8 (fp32) global_load_dwordx4 in flight before one vmcnt(0) —
// the compiler provably sinks C++-level batched loads next to the branchy
// consumer (R3: VGPR=32, 1.1 TB/s); a single asm block cannot be re-scheduled.
__global__ __launch_bounds__(256) void k_gat_row(
    const void* __restrict__ adjraw,
    const float* __restrict__ Wh,
    const float* __restrict__ Wh1, const float* __restrict__ Wh2,
    const float* __restrict__ Ca_f, const float* __restrict__ Wg_f,
    float* __restrict__ Gf,
    int* __restrict__ nbr_cnt, u16* __restrict__ nbr_idx,
    void* __restrict__ dout)
{
    const int n = blockIdx.x;
    const int tid = threadIdx.x;
    const int bf = detect_bf(adjraw);
    __shared__ int   s_cnt;
    __shared__ int   s_idx[MAXN];
    __shared__ float s_att[MAXN];
    __shared__ float s_z[H];
    __shared__ float s_g[H];
    __shared__ float s_red[256];
    __shared__ float s_sc[16];

    if (tid == 0) s_cnt = 0;
    __syncthreads();

    if (bf) {
        const u16* arow = (const u16*)adjraw + (size_t)n * N_NODES;
        const u16* p0 = arow + 0 * 2048 + tid * 8;
        const u16* p1 = arow + 1 * 2048 + tid * 8;
        const u16* p2 = arow + 2 * 2048 + tid * 8;
        const u16* p3 = arow + 3 * 2048 + tid * 8;
        u32x4 r0, r1, r2, r3;
        asm volatile(
            "global_load_dwordx4 %0, %4, off\n\t"
            "global_load_dwordx4 %1, %5, off\n\t"
            "global_load_dwordx4 %2, %6, off\n\t"
            "global_load_dwordx4 %3, %7, off\n\t"
            "s_waitcnt vmcnt(0)"
            : "=&v"(r0), "=&v"(r1), "=&v"(r2), "=&v"(r3)
            : "v"(p0), "v"(p1), "v"(p2), "v"(p3)
            : "memory");
        u32x4 rr[4] = {r0, r1, r2, r3};
        #pragma unroll
        for (int it = 0; it < 4; it++) {
            int base = it * 2048 + tid * 8;
            u32x4 v = rr[it];
            if (v[0] | v[1] | v[2] | v[3]) {            // entries are {0, 1.0bf16}
                #pragma unroll
                for (int q = 0; q < 4; q++) {
                    u32 wq = v[q];
                    if (wq & 0xFFFFu) {
                        int p = atomicAdd(&s_cnt, 1);
                        if (p < MAXN) s_idx[p] = base + q * 2;
                    }
                    if (wq >> 16) {
                        int p = atomicAdd(&s_cnt, 1);
                        if (p < MAXN) s_idx[p] = base + q * 2 + 1;
                    }
                }
            }
        }
    } else {
        const float* arow = (const float*)adjraw + (size_t)n * N_NODES;
        const float* q0 = arow + 0 * 1024 + tid * 4;
        const float* q1 = arow + 1 * 1024 + tid * 4;
        const float* q2 = arow + 2 * 1024 + tid * 4;
        const float* q3 = arow + 3 * 1024 + tid * 4;
        const float* q4 = arow + 4 * 1024 + tid * 4;
        const float* q5 = arow + 5 * 1024 + tid * 4;
        const float* q6 = arow + 6 * 1024 + tid * 4;
        const float* q7 = arow + 7 * 1024 + tid * 4;
        u32x4 r0, r1, r2, r3, r4, r5, r6, r7;
        asm volatile(
            "global_load_dwordx4 %0, %8, off\n\t"
            "global_load_dwordx4 %1, %9, off\n\t"
            "global_load_dwordx4 %2, %10, off\n\t"
            "global_load_dwordx4 %3, %11, off\n\t"
            "global_load_dwordx4 %4, %12, off\n\t"
            "global_load_dwordx4 %5, %13, off\n\t"
            "global_load_dwordx4 %6, %14, off\n\t"
            "global_load_dwordx4 %7, %15, off\n\t"
            "s_waitcnt vmcnt(0)"
            : "=&v"(r0), "=&v"(r1), "=&v"(r2), "=&v"(r3),
              "=&v"(r4), "=&v"(r5), "=&v"(r6), "=&v"(r7)
            : "v"(q0), "v"(q1), "v"(q2), "v"(q3),
              "v"(q4), "v"(q5), "v"(q6), "v"(q7)
            : "memory");
        u32x4 rr[8] = {r0, r1, r2, r3, r4, r5, r6, r7};
        #pragma unroll
        for (int it = 0; it < 8; it++) {
            int base = it * 1024 + tid * 4;
            u32x4 v = rr[it];
            if (v[0] | v[1] | v[2] | v[3]) {            // entries are {0.0f, 1.0f}
                #pragma unroll
                for (int q = 0; q < 4; q++) {
                    if (v[q]) {
                        int p = atomicAdd(&s_cnt, 1);
                        if (p < MAXN) s_idx[p] = base + q;
                    }
                }
            }
        }
    }
    __syncthreads();
    const int cnt = min(s_cnt, MAXN);
    if (tid == 0) nbr_cnt[n] = cnt;
    if (tid < cnt) nbr_idx[(size_t)n * MAXN + tid] = (u16)s_idx[tid];

    // --- softmax over cnt (<=96) entries: wave shuffle reductions ---
    float e = 0.f;
    if (tid < cnt) {
        float v = Wh1[n] + Wh2[s_idx[tid]];
        e = v > 0.f ? v : 0.2f * v;
    }
    int lane = tid & 63, wv = tid >> 6;
    float vmax = (tid < cnt) ? e : -3e38f;
    #pragma unroll
    for (int off = 32; off; off >>= 1) vmax = fmaxf(vmax, __shfl_xor(vmax, off));
    if (lane == 0) s_red[wv] = vmax;
    __syncthreads();
    float m = fmaxf(fmaxf(s_red[0], s_red[1]), fmaxf(s_red[2], s_red[3]));
    float wexp = (tid < cnt) ? expf(e - m) : 0.f;
    float ssum = wexp;
    #pragma unroll
    for (int off = 32; off; off >>= 1) ssum += __shfl_xor(ssum, off);
    if (lane == 0) s_red[8 + wv] = ssum;
    __syncthreads();
    float denom = s_red[8] + s_red[9] + s_red[10] + s_red[11];
    if (tid < cnt) s_att[tid] = wexp / denom;
    __syncthreads();

    // --- Z_0 row: att @ Wh, gather unrolled x4 for memory-level parallelism ---
    float acc = 0.f;
    {
        int t = 0;
        for (; t + 4 <= cnt; t += 4) {
            int i0 = s_idx[t], i1 = s_idx[t+1], i2 = s_idx[t+2], i3 = s_idx[t+3];
            float w0 = s_att[t], w1 = s_att[t+1], w2 = s_att[t+2], w3 = s_att[t+3];
            float x0 = Wh[(size_t)i0 * H + tid];
            float x1 = Wh[(size_t)i1 * H + tid];
            float x2 = Wh[(size_t)i2 * H + tid];
            float x3 = Wh[(size_t)i3 * H + tid];
            acc += w0 * x0; acc += w1 * x1; acc += w2 * x2; acc += w3 * x3;
        }
        for (; t < cnt; t++)
            acc += s_att[t] * Wh[(size_t)s_idx[t] * H + tid];
    }
    s_z[tid] = acc;
    store_out(dout, bf, (size_t)Z0_OFF + (size_t)n * H + tid, acc);
    s_g[tid] = acc > 0.f ? acc : expf(acc) - 1.f;
    __syncthreads();

    {
        int k = tid & 15, hb = (tid >> 4) * 16;
        float p = 0.f;
        #pragma unroll
        for (int i = 0; i < 16; i++) {
            float d = s_z[hb + i] - Ca_f[(size_t)k * H + hb + i];
            p += d * d;
        }
        s_red[tid] = p;
    }
    __syncthreads();
    if (tid < 16) {
        float d2 = 0.f;
        #pragma unroll
        for (int q = 0; q < 16; q++) d2 += s_red[q * 16 + tid];
        s_sc[tid] = expf(-sqrtf(d2)) + 1e-10f;
    }
    __syncthreads();
    if (tid < 16) {
        float tot = 0.f;
        #pragma unroll
        for (int q = 0; q < 16; q++) tot += s_sc[q];
        store_out(dout, bf, (size_t)SC_OFF + (size_t)n * K_CL + tid, s_sc[tid] / tot);
    }
    __syncthreads();

    {
        int o = tid & 15, hb = (tid >> 4) * 16;
        float p = 0.f;
        #pragma unroll
        for (int i = 0; i < 16; i++)
            p += s_g[hb + i] * Wg_f[(size_t)(hb + i) * D_OUT + o];
        s_red[tid] = p;
    }
    __syncthreads();
    if (tid < 16) {
        float g2 = 0.f;
        #pragma unroll
        for (int q = 0; q < 16; q++) g2 += s_red[q * 16 + tid];
        Gf[(size_t)n * D_OUT + tid] = g2;
    }
}

__global__ __launch_bounds__(256) void k_f1(
    const int* __restrict__ nbr_cnt, const u16* __restrict__ nbr_idx,
    const float* __restrict__ Gf, const void* __restrict__ adj,
    void* __restrict__ dout)
{
    int tid = threadIdx.x;
    int bf = detect_bf(adj);
    int r = tid >> 4, o = tid & 15;
    int n = blockIdx.x * 16 + r;
    int cnt = min(nbr_cnt[n], MAXN);
    const u16* idx = nbr_idx + (size_t)n * MAXN;
    float acc = 0.f;
    int t = 0;
    for (; t + 4 <= cnt; t += 4) {
        int i0 = idx[t], i1 = idx[t+1], i2 = idx[t+2], i3 = idx[t+3];
        float g0 = Gf[(size_t)i0 * D_OUT + o];
        float g1 = Gf[(size_t)i1 * D_OUT + o];
        float g2 = Gf[(size_t)i2 * D_OUT + o];
        float g3 = Gf[(size_t)i3 * D_OUT + o];
        acc += g0; acc += g1; acc += g2; acc += g3;
    }
    for (; t < cnt; t++)
        acc += Gf[(size_t)idx[t] * D_OUT + o];
    acc = fmaxf(acc, 0.f);
    store_out(dout, bf, (size_t)OUT_OFF + (size_t)n * D_OUT + o, acc);
    store_out(dout, bf, (size_t)Z1_OFF  + (size_t)n * D_OUT + o, acc);
}

extern "C" void kernel_launch(void* const* d_in, const int* in_sizes, int n_in,
                              void* d_out, int out_size, void* d_ws, size_t ws_size,
                              hipStream_t stream) {
    const void* x    = d_in[0];
    const void* adj  = d_in[1];
    const void* C_a  = d_in[2];
    const void* W    = d_in[3];
    const void* av   = d_in[4];
    const void* Wgcn = d_in[5];

    char* wsp = (char*)d_ws;
    float* Wh   = (float*)wsp;                 wsp += (size_t)N_NODES * H * 4;
    float* Wh1  = (float*)wsp;                 wsp += (size_t)N_NODES * 4;
    float* Wh2  = (float*)wsp;                 wsp += (size_t)N_NODES * 4;
    float* Gf   = (float*)wsp;                 wsp += (size_t)N_NODES * D_OUT * 4;
    int*   ncnt = (int*)wsp;                   wsp += (size_t)N_NODES * 4;
    u16*   nidx = (u16*)wsp;                   wsp += (size_t)N_NODES * MAXN * 2;
    float* a_f  = (float*)wsp;                 wsp += 2 * H * 4;
    float* Ca_f = (float*)wsp;                 wsp += (size_t)K_CL * H * 4;
    float* Wg_f = (float*)wsp;                 wsp += (size_t)H * D_OUT * 4;
    u16*   Wt   = (u16*)wsp;                   wsp += (size_t)H * D_IN * 2;

    k_prep    <<<66, 256, 0, stream>>>(W, av, C_a, Wgcn, adj, Wt, a_f, Ca_f, Wg_f,
                                       Wh1, Wh2);
    k_gemm_wh <<<512, 256, 0, stream>>>(x, W, Wt, adj, a_f, Wh, Wh1, Wh2);
    k_gat_row <<<N_NODES, 256, 0, stream>>>(adj, Wh, Wh1, Wh2, Ca_f, Wg_f,
                                            Gf, ncnt, nidx, d_out);
    k_f1      <<<N_NODES / 16, 256, 0, stream>>>(ncnt, nidx, Gf, adj, d_out);
}

// Round 7
// 426.956 us; speedup vs baseline: 1.1887x; 1.0056x over previous
//
#include <hip/hip_runtime.h>
#include <hip/hip_bf16.h>

#define N_NODES 8192
#define D_IN    512
#define H       256
#define D_OUT   16
#define K_CL    16
#define MAXN    96

// flat output element offsets (dtype-agnostic): output | Z_1 | Z_0 | score
#define OUT_OFF 0
#define Z1_OFF  131072
#define Z0_OFF  262144
#define SC_OFF  2359296

typedef unsigned int   u32;
typedef unsigned short u16;
typedef __attribute__((ext_vector_type(8))) short bf16x8;
typedef __attribute__((ext_vector_type(4))) float f32x4;
typedef __attribute__((ext_vector_type(4))) u32   u32x4;

__device__ __forceinline__ float load_in(const void* p, int bf, size_t idx) {
    if (bf) { u32 w = ((const u16*)p)[idx]; return __uint_as_float(w << 16); }
    return ((const float*)p)[idx];
}
__device__ __forceinline__ void store_out(void* p, int bf, size_t idx, float v) {
    if (bf) ((__hip_bfloat16*)p)[idx] = __float2bfloat16(v);
    else    ((float*)p)[idx] = v;
}
// adj = max(adj, I) guarantees adj[0][0] == 1.0.
// fp32: word0 == 0x3F800000 exactly. bf16: word0 == 0x00003F80 or 0x3F803F80.
__device__ __forceinline__ int detect_bf(const void* adj) {
    return ((const u32*)adj)[0] != 0x3F800000u;
}
__device__ __forceinline__ float bf2f(u32 h) { return __uint_as_float(h << 16); }

// merged prep: blocks 0..31 transpose W -> Wt (bf16 [H][D_IN]);
// blocks 32..65 copy small params AND zero Wh1/Wh2 (accumulated by k_gemm_scan).
__global__ __launch_bounds__(256) void k_prep(
    const void* __restrict__ wraw, const void* av, const void* C_a, const void* Wgcn,
    const void* __restrict__ adj,
    u16* __restrict__ Wt, float* a_f, float* Ca_f, float* Wg_f,
    float* __restrict__ Wh1, float* __restrict__ Wh2)
{
    int bf = detect_bf(adj);
    int b = blockIdx.x, tid = threadIdx.x;
    if (b >= 32) {
        int i = (b - 32) * 256 + tid;
        if (i < 512)        a_f[i]         = load_in(av,   bf, i);
        else if (i < 4608)  Ca_f[i - 512]  = load_in(C_a,  bf, i - 512);
        else if (i < 8704)  Wg_f[i - 4608] = load_in(Wgcn, bf, i - 4608);
        if (i < N_NODES) { Wh1[i] = 0.f; Wh2[i] = 0.f; }
        return;
    }
    __shared__ float tile[64][65];
    int k0 = (b >> 2) * 64, h0 = (b & 3) * 64;
    int hh = tid & 63, kk = tid >> 6;
    #pragma unroll
    for (int p = 0; p < 16; p++) {
        int k = kk * 16 + p;
        tile[k][hh] = load_in(wraw, bf, (size_t)(k0 + k) * H + h0 + hh);
    }
    __syncthreads();
    int kc = tid & 63, hr = tid >> 6;
    #pragma unroll
    for (int p = 0; p < 16; p++) {
        int h = hr * 16 + p;
        __hip_bfloat16 bb = __float2bfloat16(tile[kc][h]);
        Wt[(size_t)(h0 + h) * D_IN + k0 + kc] = *(u16*)&bb;
    }
}

// FUSED dispatch: blocks 0..511 = GEMM (Wh = x@W, fused Wh1/Wh2 partials);
// blocks 512..8703 = adjacency scan, one row each (asm load clause, R6-verified).
// The two roles touch disjoint data, so they overlap freely within one launch —
// the scan (HBM-bound) hides under the GEMM (latency/MFMA-bound).
__global__ __launch_bounds__(256) void k_gemm_scan(
    const void* __restrict__ xraw, const void* __restrict__ wraw,
    const u16* __restrict__ Wt, const void* __restrict__ adjraw,
    const float* __restrict__ a_f,
    float* __restrict__ Wh, float* __restrict__ Wh1, float* __restrict__ Wh2,
    int* __restrict__ nbr_cnt, u16* __restrict__ nbr_idx)
{
    int bf = detect_bf(adjraw);
    __shared__ float xs[32][68];
    __shared__ float ws_[32][68];
    __shared__ int   s_cnt;
    __shared__ int   s_idx[MAXN];
    int tid = threadIdx.x;

    if (blockIdx.x >= 512) {
        // ---------------- scan role: one adjacency row per block ----------------
        const int n = blockIdx.x - 512;
        if (tid == 0) s_cnt = 0;
        __syncthreads();
        if (bf) {
            const u16* arow = (const u16*)adjraw + (size_t)n * N_NODES;
            const u16* p0 = arow + 0 * 2048 + tid * 8;
            const u16* p1 = arow + 1 * 2048 + tid * 8;
            const u16* p2 = arow + 2 * 2048 + tid * 8;
            const u16* p3 = arow + 3 * 2048 + tid * 8;
            u32x4 r0, r1, r2, r3;
            asm volatile(
                "global_load_dwordx4 %0, %4, off\n\t"
                "global_load_dwordx4 %1, %5, off\n\t"
                "global_load_dwordx4 %2, %6, off\n\t"
                "global_load_dwordx4 %3, %7, off\n\t"
                "s_waitcnt vmcnt(0)"
                : "=&v"(r0), "=&v"(r1), "=&v"(r2), "=&v"(r3)
                : "v"(p0), "v"(p1), "v"(p2), "v"(p3)
                : "memory");
            u32x4 rr[4] = {r0, r1, r2, r3};
            #pragma unroll
            for (int it = 0; it < 4; it++) {
                int base = it * 2048 + tid * 8;
                u32x4 v = rr[it];
                if (v[0] | v[1] | v[2] | v[3]) {        // entries are {0, 1.0bf16}
                    #pragma unroll
                    for (int q = 0; q < 4; q++) {
                        u32 wq = v[q];
                        if (wq & 0xFFFFu) {
                            int p = atomicAdd(&s_cnt, 1);
                            if (p < MAXN) s_idx[p] = base + q * 2;
                        }
                        if (wq >> 16) {
                            int p = atomicAdd(&s_cnt, 1);
                            if (p < MAXN) s_idx[p] = base + q * 2 + 1;
                        }
                    }
                }
            }
        } else {
            const float* arow = (const float*)adjraw + (size_t)n * N_NODES;
            const float* q0 = arow + 0 * 1024 + tid * 4;
            const float* q1 = arow + 1 * 1024 + tid * 4;
            const float* q2 = arow + 2 * 1024 + tid * 4;
            const float* q3 = arow + 3 * 1024 + tid * 4;
            const float* q4 = arow + 4 * 1024 + tid * 4;
            const float* q5 = arow + 5 * 1024 + tid * 4;
            const float* q6 = arow + 6 * 1024 + tid * 4;
            const float* q7 = arow + 7 * 1024 + tid * 4;
            u32x4 r0, r1, r2, r3, r4, r5, r6, r7;
            asm volatile(
                "global_load_dwordx4 %0, %8, off\n\t"
                "global_load_dwordx4 %1, %9, off\n\t"
                "global_load_dwordx4 %2, %10, off\n\t"
                "global_load_dwordx4 %3, %11, off\n\t"
                "global_load_dwordx4 %4, %12, off\n\t"
                "global_load_dwordx4 %5, %13, off\n\t"
                "global_load_dwordx4 %6, %14, off\n\t"
                "global_load_dwordx4 %7, %15, off\n\t"
                "s_waitcnt vmcnt(0)"
                : "=&v"(r0), "=&v"(r1), "=&v"(r2), "=&v"(r3),
                  "=&v"(r4), "=&v"(r5), "=&v"(r6), "=&v"(r7)
                : "v"(q0), "v"(q1), "v"(q2), "v"(q3),
                  "v"(q4), "v"(q5), "v"(q6), "v"(q7)
                : "memory");
            u32x4 rr[8] = {r0, r1, r2, r3, r4, r5, r6, r7};
            #pragma unroll
            for (int it = 0; it < 8; it++) {
                int base = it * 1024 + tid * 4;
                u32x4 v = rr[it];
                if (v[0] | v[1] | v[2] | v[3]) {        // entries are {0.0f, 1.0f}
                    #pragma unroll
                    for (int q = 0; q < 4; q++) {
                        if (v[q]) {
                            int p = atomicAdd(&s_cnt, 1);
                            if (p < MAXN) s_idx[p] = base + q;
                        }
                    }
                }
            }
        }
        __syncthreads();
        const int cnt = min(s_cnt, MAXN);
        if (tid == 0) nbr_cnt[n] = cnt;
        if (tid < cnt) nbr_idx[(size_t)n * MAXN + tid] = (u16)s_idx[tid];
        return;
    }

    // ---------------- GEMM role (blocks 0..511), champion code ----------------
    int bm = blockIdx.x >> 2, bn = blockIdx.x & 3;
    int m0 = bm * 64, n0 = bn * 64;

    if (bf) {
        int wave = tid >> 6, lane = tid & 63;
        int wr = wave >> 1, wc = wave & 1;
        int r0 = m0 + wr * 32, c0 = n0 + wc * 32;
        int lr = lane & 15, lk = lane >> 4;
        const u16* xp = (const u16*)xraw;
        const u16* a0p = xp + (size_t)(r0 + lr)      * D_IN + lk * 8;
        const u16* a1p = xp + (size_t)(r0 + 16 + lr) * D_IN + lk * 8;
        const u16* b0p = Wt + (size_t)(c0 + lr)      * D_IN + lk * 8;
        const u16* b1p = Wt + (size_t)(c0 + 16 + lr) * D_IN + lk * 8;
        f32x4 acc[2][2] = {};
        #pragma unroll 4
        for (int k0 = 0; k0 < D_IN; k0 += 32) {
            bf16x8 a0 = *(const bf16x8*)(a0p + k0);
            bf16x8 a1 = *(const bf16x8*)(a1p + k0);
            bf16x8 b0 = *(const bf16x8*)(b0p + k0);
            bf16x8 b1 = *(const bf16x8*)(b1p + k0);
            acc[0][0] = __builtin_amdgcn_mfma_f32_16x16x32_bf16(a0, b0, acc[0][0], 0, 0, 0);
            acc[0][1] = __builtin_amdgcn_mfma_f32_16x16x32_bf16(a0, b1, acc[0][1], 0, 0, 0);
            acc[1][0] = __builtin_amdgcn_mfma_f32_16x16x32_bf16(a1, b0, acc[1][0], 0, 0, 0);
            acc[1][1] = __builtin_amdgcn_mfma_f32_16x16x32_bf16(a1, b1, acc[1][1], 0, 0, 0);
        }
        // C/D: col = c0+16j+(lane&15), row = r0+16i+4*(lane>>4)+reg
        float a1v0 = a_f[c0 + lr],     a1v1 = a_f[c0 + 16 + lr];
        float a2v0 = a_f[H + c0 + lr], a2v1 = a_f[H + c0 + 16 + lr];
        #pragma unroll
        for (int i = 0; i < 2; i++) {
            #pragma unroll
            for (int reg = 0; reg < 4; reg++) {
                int r = r0 + 16 * i + 4 * lk + reg;
                float v0 = acc[i][0][reg], v1 = acc[i][1][reg];
                Wh[(size_t)r * H + c0 + lr]      = v0;
                Wh[(size_t)r * H + c0 + 16 + lr] = v1;
                float s1 = a1v0 * v0 + a1v1 * v1;
                float s2 = a2v0 * v0 + a2v1 * v1;
                #pragma unroll
                for (int off = 8; off; off >>= 1) {
                    s1 += __shfl_xor(s1, off);
                    s2 += __shfl_xor(s2, off);
                }
                if (lr == 0) {
                    atomicAdd(&Wh1[r], s1);
                    atomicAdd(&Wh2[r], s2);
                }
            }
        }
        return;
    }

    // ---- fp32 VALU path ----
    int tx = tid & 15, ty = tid >> 4;
    float acc[4][4] = {};
    for (int k0 = 0; k0 < D_IN; k0 += 32) {
        {
            int r = tid >> 2, kq = (tid & 3) * 8;
            size_t base = (size_t)(m0 + r) * D_IN + k0 + kq;
            float4 f0 = *(const float4*)((const float*)xraw + base);
            float4 f1 = *(const float4*)((const float*)xraw + base + 4);
            xs[kq + 0][r] = f0.x; xs[kq + 1][r] = f0.y;
            xs[kq + 2][r] = f0.z; xs[kq + 3][r] = f0.w;
            xs[kq + 4][r] = f1.x; xs[kq + 5][r] = f1.y;
            xs[kq + 6][r] = f1.z; xs[kq + 7][r] = f1.w;
        }
        {
            int kk = tid >> 3, n8 = (tid & 7) * 8;
            size_t base = (size_t)(k0 + kk) * H + n0 + n8;
            float4 f0 = *(const float4*)((const float*)wraw + base);
            float4 f1 = *(const float4*)((const float*)wraw + base + 4);
            ws_[kk][n8+0]=f0.x; ws_[kk][n8+1]=f0.y; ws_[kk][n8+2]=f0.z; ws_[kk][n8+3]=f0.w;
            ws_[kk][n8+4]=f1.x; ws_[kk][n8+5]=f1.y; ws_[kk][n8+6]=f1.z; ws_[kk][n8+7]=f1.w;
        }
        __syncthreads();
        #pragma unroll
        for (int kk = 0; kk < 32; kk++) {
            float4 a4 = *(const float4*)&xs[kk][ty * 4];
            float4 b4 = *(const float4*)&ws_[kk][tx * 4];
            float a[4] = {a4.x, a4.y, a4.z, a4.w};
            float b[4] = {b4.x, b4.y, b4.z, b4.w};
            #pragma unroll
            for (int i = 0; i < 4; i++)
                #pragma unroll
                for (int j = 0; j < 4; j++)
                    acc[i][j] += a[i] * b[j];
        }
        __syncthreads();
    }
    float4 av1 = *(const float4*)(a_f + n0 + tx * 4);
    float4 av2 = *(const float4*)(a_f + H + n0 + tx * 4);
    #pragma unroll
    for (int i = 0; i < 4; i++) {
        float4 o = {acc[i][0], acc[i][1], acc[i][2], acc[i][3]};
        *(float4*)&Wh[(size_t)(m0 + ty*4 + i) * H + n0 + tx*4] = o;
        float s1 = o.x*av1.x + o.y*av1.y + o.z*av1.z + o.w*av1.w;
        float s2 = o.x*av2.x + o.y*av2.y + o.z*av2.z + o.w*av2.w;
        #pragma unroll
        for (int off = 8; off; off >>= 1) {
            s1 += __shfl_xor(s1, off);
            s2 += __shfl_xor(s2, off);
        }
        if (tx == 0) {
            atomicAdd(&Wh1[m0 + ty*4 + i], s1);
            atomicAdd(&Wh2[m0 + ty*4 + i], s2);
        }
    }
}

// block-per-row; scan moved to k_gemm_scan — loads nidx, then softmax+gather+epilogue.
__global__ __launch_bounds__(256) void k_gat_row(
    const int* __restrict__ ncnt, const u16* __restrict__ nidx,
    const float* __restrict__ Wh,
    const float* __restrict__ Wh1, const float* __restrict__ Wh2,
    const float* __restrict__ Ca_f, const float* __restrict__ Wg_f,
    float* __restrict__ Gf, const void* __restrict__ adjraw,
    void* __restrict__ dout)
{
    const int n = blockIdx.x;
    const int tid = threadIdx.x;
    const int bf = detect_bf(adjraw);
    __shared__ int   s_idx[MAXN];
    __shared__ float s_att[MAXN];
    __shared__ float s_z[H];
    __shared__ float s_g[H];
    __shared__ float s_red[256];
    __shared__ float s_sc[16];

    const int cnt = min(ncnt[n], MAXN);
    if (tid < cnt) s_idx[tid] = nidx[(size_t)n * MAXN + tid];
    __syncthreads();

    // --- softmax over cnt (<=96) entries: wave shuffle reductions ---
    float e = 0.f;
    if (tid < cnt) {
        float v = Wh1[n] + Wh2[s_idx[tid]];
        e = v > 0.f ? v : 0.2f * v;
    }
    int lane = tid & 63, wv = tid >> 6;
    float vmax = (tid < cnt) ? e : -3e38f;
    #pragma unroll
    for (int off = 32; off; off >>= 1) vmax = fmaxf(vmax, __shfl_xor(vmax, off));
    if (lane == 0) s_red[wv] = vmax;
    __syncthreads();
    float m = fmaxf(fmaxf(s_red[0], s_red[1]), fmaxf(s_red[2], s_red[3]));
    float wexp = (tid < cnt) ? expf(e - m) : 0.f;
    float ssum = wexp;
    #pragma unroll
    for (int off = 32; off; off >>= 1) ssum += __shfl_xor(ssum, off);
    if (lane == 0) s_red[8 + wv] = ssum;
    __syncthreads();
    float denom = s_red[8] + s_red[9] + s_red[10] + s_red[11];
    if (tid < cnt) s_att[tid] = wexp / denom;
    __syncthreads();

    // --- Z_0 row: att @ Wh, gather unrolled x4 for memory-level parallelism ---
    float acc = 0.f;
    {
        int t = 0;
        for (; t + 4 <= cnt; t += 4) {
            int i0 = s_idx[t], i1 = s_idx[t+1], i2 = s_idx[t+2], i3 = s_idx[t+3];
            float w0 = s_att[t], w1 = s_att[t+1], w2 = s_att[t+2], w3 = s_att[t+3];
            float x0 = Wh[(size_t)i0 * H + tid];
            float x1 = Wh[(size_t)i1 * H + tid];
            float x2 = Wh[(size_t)i2 * H + tid];
            float x3 = Wh[(size_t)i3 * H + tid];
            acc += w0 * x0; acc += w1 * x1; acc += w2 * x2; acc += w3 * x3;
        }
        for (; t < cnt; t++)
            acc += s_att[t] * Wh[(size_t)s_idx[t] * H + tid];
    }
    s_z[tid] = acc;
    store_out(dout, bf, (size_t)Z0_OFF + (size_t)n * H + tid, acc);
    s_g[tid] = acc > 0.f ? acc : expf(acc) - 1.f;
    __syncthreads();

    {
        int k = tid & 15, hb = (tid >> 4) * 16;
        float p = 0.f;
        #pragma unroll
        for (int i = 0; i < 16; i++) {
            float d = s_z[hb + i] - Ca_f[(size_t)k * H + hb + i];
            p += d * d;
        }
        s_red[tid] = p;
    }
    __syncthreads();
    if (tid < 16) {
        float d2 = 0.f;
        #pragma unroll
        for (int q = 0; q < 16; q++) d2 += s_red[q * 16 + tid];
        s_sc[tid] = expf(-sqrtf(d2)) + 1e-10f;
    }
    __syncthreads();
    if (tid < 16) {
        float tot = 0.f;
        #pragma unroll
        for (int q = 0; q < 16; q++) tot += s_sc[q];
        store_out(dout, bf, (size_t)SC_OFF + (size_t)n * K_CL + tid, s_sc[tid] / tot);
    }
    __syncthreads();

    {
        int o = tid & 15, hb = (tid >> 4) * 16;
        float p = 0.f;
        #pragma unroll
        for (int i = 0; i < 16; i++)
            p += s_g[hb + i] * Wg_f[(size_t)(hb + i) * D_OUT + o];
        s_red[tid] = p;
    }
    __syncthreads();
    if (tid < 16) {
        float g2 = 0.f;
        #pragma unroll
        for (int q = 0; q < 16; q++) g2 += s_red[q * 16 + tid];
        Gf[(size_t)n * D_OUT + tid] = g2;
    }
}

__global__ __launch_bounds__(256) void k_f1(
    const int* __restrict__ nbr_cnt, const u16* __restrict__ nbr_idx,
    const float* __restrict__ Gf, const void* __restrict__ adj,
    void* __restrict__ dout)
{
    int tid = threadIdx.x;
    int bf = detect_bf(adj);
    int r = tid >> 4, o = tid & 15;
    int n = blockIdx.x * 16 + r;
    int cnt = min(nbr_cnt[n], MAXN);
    const u16* idx = nbr_idx + (size_t)n * MAXN;
    float acc = 0.f;
    int t = 0;
    for (; t + 4 <= cnt; t += 4) {
        int i0 = idx[t], i1 = idx[t+1], i2 = idx[t+2], i3 = idx[t+3];
        float g0 = Gf[(size_t)i0 * D_OUT + o];
        float g1 = Gf[(size_t)i1 * D_OUT + o];
        float g2 = Gf[(size_t)i2 * D_OUT + o];
        float g3 = Gf[(size_t)i3 * D_OUT + o];
        acc += g0; acc += g1; acc += g2; acc += g3;
    }
    for (; t < cnt; t++)
        acc += Gf[(size_t)idx[t] * D_OUT + o];
    acc = fmaxf(acc, 0.f);
    store_out(dout, bf, (size_t)OUT_OFF + (size_t)n * D_OUT + o, acc);
    store_out(dout, bf, (size_t)Z1_OFF  + (size_t)n * D_OUT + o, acc);
}

extern "C" void kernel_launch(void* const* d_in, const int* in_sizes, int n_in,
                              void* d_out, int out_size, void* d_ws, size_t ws_size,
                              hipStream_t stream) {
    const void* x    = d_in[0];
    const void* adj  = d_in[1];
    const void* C_a  = d_in[2];
    const void* W    = d_in[3];
    const void* av   = d_in[4];
    const void* Wgcn = d_in[5];

    char* wsp = (char*)d_ws;
    float* Wh   = (float*)wsp;                 wsp += (size_t)N_NODES * H * 4;
    float* Wh1  = (float*)wsp;                 wsp += (size_t)N_NODES * 4;
    float* Wh2  = (float*)wsp;                 wsp += (size_t)N_NODES * 4;
    float* Gf   = (float*)wsp;                 wsp += (size_t)N_NODES * D_OUT * 4;
    int*   ncnt = (int*)wsp;                   wsp += (size_t)N_NODES * 4;
    u16*   nidx = (u16*)wsp;                   wsp += (size_t)N_NODES * MAXN * 2;
    float* a_f  = (float*)wsp;                 wsp += 2 * H * 4;
    float* Ca_f = (float*)wsp;                 wsp += (size_t)K_CL * H * 4;
    float* Wg_f = (float*)wsp;                 wsp += (size_t)H * D_OUT * 4;
    u16*   Wt   = (u16*)wsp;                   wsp += (size_t)H * D_IN * 2;

    k_prep      <<<66, 256, 0, stream>>>(W, av, C_a, Wgcn, adj, Wt, a_f, Ca_f, Wg_f,
                                         Wh1, Wh2);
    k_gemm_scan <<<512 + N_NODES, 256, 0, stream>>>(x, W, Wt, adj, a_f,
                                                    Wh, Wh1, Wh2, ncnt, nidx);
    k_gat_row   <<<N_NODES, 256, 0, stream>>>(ncnt, nidx, Wh, Wh1, Wh2, Ca_f, Wg_f,
                                              Gf, adj, d_out);
    k_f1        <<<N_NODES / 16, 256, 0, stream>>>(ncnt, nidx, Gf, adj, d_out);
}